// Round 11
// baseline (132.805 us; speedup 1.0000x reference)
//
#include <hip/hip_runtime.h>
#include <hip/hip_bf16.h>

// Shapes: x(8,16,4,64,64) f32, W(256,16,5,5) f32, b(1,1,8,32) f32
// out(8,32,8,64,64) f32.
//
// Reference reshapes (verified passing R1/R2/R4/R6/R9/R10):
//   conv input  t2[n,a,h,w] = x[b0, fl&15, ci, fl>>10, (fl>>4)&63],
//     fl = a*4096 + h*64 + w, n = ci*8 + b0
//   votes flat (n,oc,y,x) reinterpreted by routing as (bv,civ,h,w,o,ao)
//     with n = bv*4 + civ.
// Conv = implicit GEMM on v_mfma_f32_16x16x32_f16 (measured layouts m89/m120).
//
// LEDGER:
//  - Softmax max-subtract removal: FAILED R3+R5 (absmax 0.78515625). Do not re-try.
//  - Inline-asm permlane swap hardening variants: FAILED (R7, R8). The original
//    single-instruction "+v","+v" form passes in routing4's codegen context;
//    builtin __builtin_amdgcn_permlane*_swap also works (R9). Routing FROZEN.
//  - Routing ILP x2 (R9) and TLP x2 (R2): both ~neutral -> routing not
//    latency-exposed; no further routing work.
//  - pack2 1024-thread (R10): neutral; kept.
//  - Cleared: conv 8wave/32oc restructure (R4), conv 2-stage reg pipeline (R6).
//  - Under test this round (conv only, value-identical): aw prefetch depth 2 +
//    __launch_bounds__(512,4) occupancy guarantee (2 blocks/CU).

typedef _Float16 half8 __attribute__((ext_vector_type(8)));
typedef _Float16 half4v __attribute__((ext_vector_type(4)));
typedef float floatx4 __attribute__((ext_vector_type(4)));

#define EPSF 1e-7f

// ---------- cross-lane reductions at VALU rate (no ds_bpermute/swizzle) ----------
template <int CTRL>
__device__ __forceinline__ float dppmov(float x) {
  return __int_as_float(__builtin_amdgcn_update_dpp(
      0, __float_as_int(x), CTRL, 0xf, 0xf, false));
}
// reduce-add over lane bits 0..2 (atoms): ^1, ^2, then ^7 half-mirror completes 8-group.
__device__ __forceinline__ float red_a_add(float x) {
  x += dppmov<0xB1>(x);   // quad_perm [1,0,3,2] : ^1
  x += dppmov<0x4E>(x);   // quad_perm [2,3,0,1] : ^2
  x += dppmov<0x141>(x);  // row_half_mirror     : ^7
  return x;
}
// reduce over lane bits 3..5 (capsule o): ^8 = row_ror:8, ^16/^32 = permlane swaps
// (R2/R4/R6/R10-passing inline-asm single-instruction form).
__device__ __forceinline__ float red_o_add(float x) {
  x += dppmov<0x128>(x);  // row_ror:8 == ^8
  { float a = x, b = x;
    asm("v_permlane16_swap_b32 %0, %1" : "+v"(a), "+v"(b));
    x = a + b; }
  { float a = x, b = x;
    asm("v_permlane32_swap_b32 %0, %1" : "+v"(a), "+v"(b));
    x = a + b; }
  return x;
}
__device__ __forceinline__ float red_o_max(float x) {
  x = fmaxf(x, dppmov<0x128>(x));
  { float a = x, b = x;
    asm("v_permlane16_swap_b32 %0, %1" : "+v"(a), "+v"(b));
    x = fmaxf(a, b); }
  { float a = x, b = x;
    asm("v_permlane32_swap_b32 %0, %1" : "+v"(a), "+v"(b));
    x = fmaxf(a, b); }
  return x;
}

// LDS-tile transpose pack: x -> th (n, a0h, h, w, 8a) f16.  (R10 text)
__global__ __launch_bounds__(1024) void k_pack2(const float* __restrict__ x,
                                                _Float16* __restrict__ th) {
  __shared__ float lin[32 * 306 + 18];
  const int bid = blockIdx.x;            // 256 blocks
  const int n   = bid >> 3;
  const int a0h = (bid >> 2) & 1;
  const int W0  = (bid & 3) * 16;
  const int ci = n >> 3, b0 = n & 7;
  const int tid = threadIdx.x;           // 0..1023
  const float* xb = x + b0 * 262144 + ci * 4096 + W0;

  for (int p = 0; p < 2; ++p) {
    int rr = p * 256 + (tid >> 2);       // 0..511  (a1=rr>>5, m=rr&31)
    int q  = (tid & 3) * 4;
    int a1 = rr >> 5, m = rr & 31;
    float4 v = *(const float4*)(xb + a1 * 16384 + (a0h * 32 + m) * 64 + q);
    float* d = lin + m * 306 + a1 * 18 + q;
    d[0] = v.x; d[1] = v.y; d[2] = v.z; d[3] = v.w;
  }
  __syncthreads();

  _Float16* tb = th + (size_t)n * 65536 + a0h * 32768 + W0 * 128;
  {
    int hh = tid >> 8;                   // 0..3
    int w1 = (tid >> 4) & 15;
    int a1 = tid & 15;
    half8 v;
#pragma unroll
    for (int j = 0; j < 8; ++j)
      v[j] = (_Float16)lin[(j * 4 + hh) * 306 + a1 * 18 + w1];
    *(half8*)(tb + hh * 8192 + w1 * 128 + a1 * 8) = v;
  }
}

// W (oc,a,ky,kx) f32 -> Wp (kk=0..25, oc, a) f16; plane kk==25 is zeros. (unchanged)
__global__ __launch_bounds__(256) void k_packw(const float* __restrict__ W,
                                               _Float16* __restrict__ Wp) {
  int id = blockIdx.x * 256 + threadIdx.x;      // 106,496 = 26*4096
  int a  = id & 15;
  int oc = (id >> 4) & 255;
  int kk = id >> 12;
  Wp[id] = (kk < 25) ? (_Float16)W[oc * 400 + a * 25 + kk] : (_Float16)0.0f;
}

// Conv v7: R6 pipeline with aw (L2 weight) prefetch deepened to 2 steps and
// a (512,4) occupancy guarantee (VGPR<=128 -> 2 blocks/CU, 4 waves/SIMD).
// Loads, addresses and MFMA accumulation order identical to R6 -> votes
// bit-identical.
__global__ __launch_bounds__(512, 4) void k_conv(const _Float16* __restrict__ th,
                                                 const _Float16* __restrict__ Wp,
                                                 _Float16* __restrict__ votes) {
  __shared__ _Float16 lds[16384];   // input tile [0,5440); epilogue reuses 32KB
  const int orig = blockIdx.x;      // 2048
  const int lid  = (orig & 7) * 256 + (orig >> 3);   // bijective (2048 % 8 == 0)
  const int y = lid & 63;
  const int n = lid >> 6;
  const int tid = threadIdx.x;

  for (int c = tid; c < 680; c += 512) {
    int a0h = c / 340;
    int rem = c - a0h * 340;
    int r   = rem / 68;
    int col = rem - r * 68;
    int row = y + r - 2;
    half8 v = {};
    if (col >= 2 && col <= 65 && row >= 0 && row < 64)
      v = *(const half8*)(th + (size_t)(((n * 2 + a0h) * 64 + row) * 64 + (col - 2)) * 8);
    *(half8*)(lds + c * 8) = v;
  }
  __syncthreads();

  const int lane  = tid & 63;
  const int wv    = tid >> 6;       // 0..7
  const int col16 = lane & 15;
  const int quad  = lane >> 4;      // 0..3
  const int t     = quad >> 1;      // tap-within-pair
  const int a0h   = quad & 1;       // atom-half
  const int m0    = wv * 32;

  floatx4 acc[2][4] = {};

  const _Float16* wbase = Wp + (size_t)t * 4096 + (m0 + col16) * 16 + a0h * 8;
  const _Float16* lbase = lds + (a0h * 340 + col16) * 8;

  half8 bfc[4], bfn[4], aw0[2], aw1[2], aw2[2];
  {
    // s = 0 taps: k0=0 -> e0=0, k1=1 -> e1=1
    const _Float16* lb = lbase + (t ? 1 : 0) * 8;
#pragma unroll
    for (int xt = 0; xt < 4; ++xt)
      bfc[xt] = *(const half8*)(lb + xt * 128);
#pragma unroll
    for (int oct = 0; oct < 2; ++oct) {
      aw0[oct] = *(const half8*)(wbase + oct * 256);            // aw(0)
      aw1[oct] = *(const half8*)(wbase + 8192 + oct * 256);     // aw(1)
    }
  }

#pragma unroll
  for (int s = 0; s < 13; ++s) {
    if (s < 11) {
#pragma unroll
      for (int oct = 0; oct < 2; ++oct)
        aw2[oct] = *(const half8*)(wbase + (size_t)(s + 2) * 8192 + oct * 256);
    }
    if (s < 12) {
      const int k0 = 2 * (s + 1);
      const int k1 = (2 * (s + 1) + 1 > 24) ? 24 : 2 * (s + 1) + 1;
      const int e0 = (k0 / 5) * 68 + (k0 % 5);
      const int e1 = (k1 / 5) * 68 + (k1 % 5);
      const _Float16* lb = lbase + (t ? e1 : e0) * 8;
#pragma unroll
      for (int xt = 0; xt < 4; ++xt)
        bfn[xt] = *(const half8*)(lb + xt * 128);
    }
#pragma unroll
    for (int oct = 0; oct < 2; ++oct)
#pragma unroll
      for (int xt = 0; xt < 4; ++xt)
        acc[oct][xt] = __builtin_amdgcn_mfma_f32_16x16x32_f16(
            aw0[oct], bfc[xt], acc[oct][xt], 0, 0, 0);
    if (s < 12) {
#pragma unroll
      for (int xt = 0; xt < 4; ++xt) bfc[xt] = bfn[xt];
#pragma unroll
      for (int oct = 0; oct < 2; ++oct) aw0[oct] = aw1[oct];
      if (s < 11) {
#pragma unroll
        for (int oct = 0; oct < 2; ++oct) aw1[oct] = aw2[oct];
      }
    }
  }

  // ---- epilogue: staged writeout (swizzle sw=(oc&15)>>1) ----
  __syncthreads();
#pragma unroll
  for (int oct = 0; oct < 2; ++oct)
#pragma unroll
    for (int xt = 0; xt < 4; ++xt)
#pragma unroll
      for (int r = 0; r < 4; ++r) {
        int oc = m0 + oct * 16 + quad * 4 + r;
        int xx = xt * 16 + col16;
        int sw = (oc & 15) >> 1;
        lds[oc * 64 + (xx ^ (sw << 3))] = (_Float16)acc[oct][xt][r];
      }
  __syncthreads();
  _Float16* vb2 = votes + (size_t)n * 1048576 + y * 64;
#pragma unroll
  for (int it = 0; it < 4; ++it) {
    int idx = it * 512 + tid;          // 2048 half8 chunks
    int oc  = idx >> 3;
    int x0  = (idx & 7) << 3;
    int sw  = (oc & 15) >> 1;
    half8 hv = *(const half8*)(lds + oc * 64 + (x0 ^ (sw << 3)));
    *(half8*)(vb2 + (size_t)oc * 4096 + x0) = hv;
  }
}

// Routing v4: EXACT R2/R4/R6/R10-passing version (frozen — see LEDGER).
__global__ __launch_bounds__(256) void k_routing4(
    const _Float16* __restrict__ votes, const float* __restrict__ bias,
    float* __restrict__ out) {
  __shared__ float so[256 * 20];        // 20 KB
  const int tid  = threadIdx.x;
  const int lane = tid & 63;
  const int wv   = tid >> 6;
  const int bid  = blockIdx.x;          // 2048
  const int bv = bid >> 8;
  const int h  = (bid >> 2) & 63;
  const int W0 = (bid & 3) * 16;

  float4 bia = *(const float4*)(bias + lane * 4);
  const int o     = lane >> 3;
  const int a0    = (lane & 7) * 4;
  const int shift = a0 >> 2;            // so[] column swizzle for this lane's rows
  float bb[4] = {bia.x, bia.y, bia.z, bia.w};

  for (int k = 0; k < 4; ++k) {
    const int wl = wv * 4 + k;          // 0..15
    const int w  = W0 + wl;
    const _Float16* vb = votes + (size_t)bv * 4194304 + h * 16384 + w * 256 + lane * 4;
    float v[4][4];
#pragma unroll
    for (int i = 0; i < 4; ++i) {
      half4v hv = *(const half4v*)(vb + (size_t)i * 1048576);
#pragma unroll
      for (int j = 0; j < 4; ++j) v[i][j] = (float)hv[j];
    }

    float logit[4], act[4], pr[4];

    // ---- round 0: logits==0 -> route==1/8 exactly; skip the softmax ----
#pragma unroll
    for (int j = 0; j < 4; ++j)
      pr[j] = fmaf(0.125f, (v[0][j] + v[1][j]) + (v[2][j] + v[3][j]), bb[j]);
    {
      float sq = pr[0]*pr[0] + pr[1]*pr[1] + pr[2]*pr[2] + pr[3]*pr[3];
      sq = red_a_add(sq);
      float sc = sq * __builtin_amdgcn_rcpf(1.f + sq)
                    * __builtin_amdgcn_rsqf(sq + EPSF);
#pragma unroll
      for (int j = 0; j < 4; ++j) act[j] = pr[j] * sc;
    }
#pragma unroll
    for (int i = 0; i < 4; ++i) {
      float ag = v[i][0]*act[0] + v[i][1]*act[1] + v[i][2]*act[2] + v[i][3]*act[3];
      logit[i] = red_a_add(ag);
    }

    // ---- rounds 1,2 ----
#pragma unroll
    for (int r = 1; r < 3; ++r) {
      float route[4];
#pragma unroll
      for (int i = 0; i < 4; ++i) {
        float m = red_o_max(logit[i]);
        float e = __expf(logit[i] - m);
        float s = red_o_add(e);
        route[i] = e * __builtin_amdgcn_rcpf(s);
      }
#pragma unroll
      for (int j = 0; j < 4; ++j) pr[j] = bb[j];
#pragma unroll
      for (int i = 0; i < 4; ++i)
#pragma unroll
        for (int j = 0; j < 4; ++j)
          pr[j] = fmaf(route[i], v[i][j], pr[j]);
      float sq = pr[0]*pr[0] + pr[1]*pr[1] + pr[2]*pr[2] + pr[3]*pr[3];
      sq = red_a_add(sq);
      float sc = sq * __builtin_amdgcn_rcpf(1.f + sq)
                    * __builtin_amdgcn_rsqf(sq + EPSF);
#pragma unroll
      for (int j = 0; j < 4; ++j) act[j] = pr[j] * sc;
      if (r < 2) {
#pragma unroll
        for (int i = 0; i < 4; ++i) {
          float ag = v[i][0]*act[0] + v[i][1]*act[1] + v[i][2]*act[2] + v[i][3]*act[3];
          logit[i] += red_a_add(ag);
        }
      }
    }

    // stage: row = (a0+j)*8 + o, col = wl ^ (row>>5)  (row>>5 == a0>>2)
#pragma unroll
    for (int j = 0; j < 4; ++j)
      so[((a0 + j) * 8 + o) * 20 + (wl ^ shift)] = act[j];
  }
  __syncthreads();

  // Coalesced writeout: 256 rows x 16 floats; de-swizzle per (p, tid):
  // s = r>>5, float4 base = w0 ^ (s&4), component permute j ^ (s&3).
  float* ob = out + (size_t)bv * 1048576 + h * 64 + W0;
#pragma unroll
  for (int p = 0; p < 4; ++p) {
    int r  = p * 64 + (tid >> 2);
    int w0 = (tid & 3) * 4;
    int s  = r >> 5;
    float4 tv = *(const float4*)(so + r * 20 + (w0 ^ (s & 4)));
    float tt[4] = {tv.x, tv.y, tv.z, tv.w};
    const int pm = s & 3;
    float4 u = make_float4(tt[0 ^ pm], tt[1 ^ pm], tt[2 ^ pm], tt[3 ^ pm]);
    *(float4*)(ob + (size_t)r * 4096 + w0) = u;
  }
}

extern "C" void kernel_launch(void* const* d_in, const int* in_sizes, int n_in,
                              void* d_out, int out_size, void* d_ws, size_t ws_size,
                              hipStream_t stream) {
  const float* x  = (const float*)d_in[0];
  const float* W  = (const float*)d_in[1];
  const float* b  = (const float*)d_in[2];
  float* out = (float*)d_out;

  _Float16* th    = (_Float16*)d_ws;            // 2,097,152 halves (4 MB)
  _Float16* Wp    = th + 2097152;               // 106,496 halves (208 KB)
  _Float16* votes = Wp + 106496;                // 33,554,432 halves (64 MB)

  k_pack2<<<256, 1024, 0, stream>>>(x, th);
  k_packw<<<416, 256, 0, stream>>>(W, Wp);
  k_conv<<<2048, 512, 0, stream>>>(th, Wp, votes);
  k_routing4<<<2048, 256, 0, stream>>>(votes, b, out);
}

// Round 12
// 128.962 us; speedup vs baseline: 1.0298x; 1.0298x over previous
//
#include <hip/hip_runtime.h>
#include <hip/hip_bf16.h>

// Shapes: x(8,16,4,64,64) f32, W(256,16,5,5) f32, b(1,1,8,32) f32
// out(8,32,8,64,64) f32.
//
// Reference reshapes (verified passing through R10):
//   conv input  t2[n,a,h,w] = x[b0, fl&15, ci, fl>>10, (fl>>4)&63],
//     fl = a*4096 + h*64 + w, n = ci*8 + b0
//   votes flat (n,oc,y,x) reinterpreted by routing as (bv,civ,h,w,o,ao):
//     value(civ,o,ao)@(h,w) = votes[(bv*4+civ)*1048576 + h*16384 + w*256 + o*32 + ao]
// Conv = implicit GEMM on v_mfma_f32_16x16x32_f16 (measured layouts m89/m120).
//
// LEDGER:
//  - Softmax max-subtract removal: FAILED R3+R5. Do not re-try (kept).
//  - Inline-asm permlane swap: FAILED under codegen perturbation (R7/R8; likely
//    also the real cause of R3/R5). ALL asm deleted; builtins only (R9-proven).
//  - Routing TLP x2 (R2) and ILP x2 (R9): null -> routing is VALU-issue-bound.
//    This round: 2-positions-per-wave (32 lanes/position, 8 atoms/lane) cuts
//    per-position instruction count ~1.5x. Sum-reduces reassociate (~1ulp);
//    max-reduce exact.
//  - conv scheduling: R6 2-stage pipeline is best (R11 deeper prefetch: worse).
//    conv reverted to R6-exact text.

typedef _Float16 half8 __attribute__((ext_vector_type(8)));
typedef _Float16 half4v __attribute__((ext_vector_type(4)));
typedef float floatx4 __attribute__((ext_vector_type(4)));
typedef unsigned uint2v __attribute__((ext_vector_type(2)));

#define EPSF 1e-7f

// ---------- cross-lane reductions (builtins ONLY; no inline asm) ----------
template <int CTRL>
__device__ __forceinline__ float dppmov(float x) {
  return __int_as_float(__builtin_amdgcn_update_dpp(
      0, __float_as_int(x), CTRL, 0xf, 0xf, false));
}
// sum over lane bits 0..1 (atom group g): exact XOR butterfly.
__device__ __forceinline__ float red_g_add(float x) {
  x += dppmov<0xB1>(x);   // quad_perm [1,0,3,2] : ^1
  x += dppmov<0x4E>(x);   // quad_perm [2,3,0,1] : ^2
  return x;
}
// sum over lane bits 2..4 (capsule o, within each 32-lane half):
// ror4+ror8 cover bits 2,3 (rotation-reduce; ~1ulp lane-order wiggle),
// permlane16_swap builtin covers bit 4 (^16). Half (bit 5) never crossed.
__device__ __forceinline__ float red_o2_add(float x) {
  x += dppmov<0x124>(x);  // row_ror:4
  x += dppmov<0x128>(x);  // row_ror:8
  uint2v r = __builtin_amdgcn_permlane16_swap(
      __float_as_uint(x), __float_as_uint(x), false, false);
  return __uint_as_float(r[0]) + __uint_as_float(r[1]);
}
__device__ __forceinline__ float red_o2_max(float x) {
  x = fmaxf(x, dppmov<0x124>(x));
  x = fmaxf(x, dppmov<0x128>(x));
  uint2v r = __builtin_amdgcn_permlane16_swap(
      __float_as_uint(x), __float_as_uint(x), false, false);
  return fmaxf(__uint_as_float(r[0]), __uint_as_float(r[1]));
}

// LDS-tile transpose pack: x -> th (n, a0h, h, w, 8a) f16.  (R10 text)
__global__ __launch_bounds__(1024) void k_pack2(const float* __restrict__ x,
                                                _Float16* __restrict__ th) {
  __shared__ float lin[32 * 306 + 18];
  const int bid = blockIdx.x;            // 256 blocks
  const int n   = bid >> 3;
  const int a0h = (bid >> 2) & 1;
  const int W0  = (bid & 3) * 16;
  const int ci = n >> 3, b0 = n & 7;
  const int tid = threadIdx.x;           // 0..1023
  const float* xb = x + b0 * 262144 + ci * 4096 + W0;

  for (int p = 0; p < 2; ++p) {
    int rr = p * 256 + (tid >> 2);
    int q  = (tid & 3) * 4;
    int a1 = rr >> 5, m = rr & 31;
    float4 v = *(const float4*)(xb + a1 * 16384 + (a0h * 32 + m) * 64 + q);
    float* d = lin + m * 306 + a1 * 18 + q;
    d[0] = v.x; d[1] = v.y; d[2] = v.z; d[3] = v.w;
  }
  __syncthreads();

  _Float16* tb = th + (size_t)n * 65536 + a0h * 32768 + W0 * 128;
  {
    int hh = tid >> 8;
    int w1 = (tid >> 4) & 15;
    int a1 = tid & 15;
    half8 v;
#pragma unroll
    for (int j = 0; j < 8; ++j)
      v[j] = (_Float16)lin[(j * 4 + hh) * 306 + a1 * 18 + w1];
    *(half8*)(tb + hh * 8192 + w1 * 128 + a1 * 8) = v;
  }
}

// W (oc,a,ky,kx) f32 -> Wp (kk=0..25, oc, a) f16; plane kk==25 is zeros.
__global__ __launch_bounds__(256) void k_packw(const float* __restrict__ W,
                                               _Float16* __restrict__ Wp) {
  int id = blockIdx.x * 256 + threadIdx.x;      // 106,496 = 26*4096
  int a  = id & 15;
  int oc = (id >> 4) & 255;
  int kk = id >> 12;
  Wp[id] = (kk < 25) ? (_Float16)W[oc * 400 + a * 25 + kk] : (_Float16)0.0f;
}

// Conv: R6's EXACT passing version (2-stage reg pipeline).
__global__ __launch_bounds__(512) void k_conv(const _Float16* __restrict__ th,
                                              const _Float16* __restrict__ Wp,
                                              _Float16* __restrict__ votes) {
  __shared__ _Float16 lds[16384];
  const int orig = blockIdx.x;      // 2048
  const int lid  = (orig & 7) * 256 + (orig >> 3);   // bijective (2048 % 8 == 0)
  const int y = lid & 63;
  const int n = lid >> 6;
  const int tid = threadIdx.x;

  for (int c = tid; c < 680; c += 512) {
    int a0h = c / 340;
    int rem = c - a0h * 340;
    int r   = rem / 68;
    int col = rem - r * 68;
    int row = y + r - 2;
    half8 v = {};
    if (col >= 2 && col <= 65 && row >= 0 && row < 64)
      v = *(const half8*)(th + (size_t)(((n * 2 + a0h) * 64 + row) * 64 + (col - 2)) * 8);
    *(half8*)(lds + c * 8) = v;
  }
  __syncthreads();

  const int lane  = tid & 63;
  const int wv    = tid >> 6;
  const int col16 = lane & 15;
  const int quad  = lane >> 4;
  const int t     = quad >> 1;
  const int a0h   = quad & 1;
  const int m0    = wv * 32;

  floatx4 acc[2][4] = {};

  const _Float16* wbase = Wp + (size_t)t * 4096 + (m0 + col16) * 16 + a0h * 8;
  const _Float16* lbase = lds + (a0h * 340 + col16) * 8;

  half8 bfc[4], awc[2], bfn[4], awn[2];
  {
    const _Float16* lb = lbase + (t ? 1 : 0) * 8;
#pragma unroll
    for (int xt = 0; xt < 4; ++xt)
      bfc[xt] = *(const half8*)(lb + xt * 128);
#pragma unroll
    for (int oct = 0; oct < 2; ++oct)
      awc[oct] = *(const half8*)(wbase + oct * 256);
  }

#pragma unroll
  for (int s = 0; s < 13; ++s) {
    if (s < 12) {
      const int k0 = 2 * (s + 1);
      const int k1 = (2 * (s + 1) + 1 > 24) ? 24 : 2 * (s + 1) + 1;
      const int e0 = (k0 / 5) * 68 + (k0 % 5);
      const int e1 = (k1 / 5) * 68 + (k1 % 5);
      const _Float16* lb = lbase + (t ? e1 : e0) * 8;
#pragma unroll
      for (int xt = 0; xt < 4; ++xt)
        bfn[xt] = *(const half8*)(lb + xt * 128);
#pragma unroll
      for (int oct = 0; oct < 2; ++oct)
        awn[oct] = *(const half8*)(wbase + (size_t)(s + 1) * 8192 + oct * 256);
    }
#pragma unroll
    for (int oct = 0; oct < 2; ++oct)
#pragma unroll
      for (int xt = 0; xt < 4; ++xt)
        acc[oct][xt] = __builtin_amdgcn_mfma_f32_16x16x32_f16(
            awc[oct], bfc[xt], acc[oct][xt], 0, 0, 0);
    if (s < 12) {
#pragma unroll
      for (int xt = 0; xt < 4; ++xt) bfc[xt] = bfn[xt];
#pragma unroll
      for (int oct = 0; oct < 2; ++oct) awc[oct] = awn[oct];
    }
  }

  __syncthreads();
#pragma unroll
  for (int oct = 0; oct < 2; ++oct)
#pragma unroll
    for (int xt = 0; xt < 4; ++xt)
#pragma unroll
      for (int r = 0; r < 4; ++r) {
        int oc = m0 + oct * 16 + quad * 4 + r;
        int xx = xt * 16 + col16;
        int sw = (oc & 15) >> 1;
        lds[oc * 64 + (xx ^ (sw << 3))] = (_Float16)acc[oct][xt][r];
      }
  __syncthreads();
  _Float16* vb2 = votes + (size_t)n * 1048576 + y * 64;
#pragma unroll
  for (int it = 0; it < 4; ++it) {
    int idx = it * 512 + tid;
    int oc  = idx >> 3;
    int x0  = (idx & 7) << 3;
    int sw  = (oc & 15) >> 1;
    half8 hv = *(const half8*)(lds + oc * 64 + (x0 ^ (sw << 3)));
    *(half8*)(vb2 + (size_t)oc * 4096 + x0) = hv;
  }
}

// Routing v9: 2 positions per wave — lanes 0-31 own position A, 32-63 own B.
// Per 32-lane half: o = (lane>>2)&7, g = lane&3 (8 atoms in-lane, ao = g*8+j).
// Same math/rounds as routing4 (max-subtract PRESENT); reduces via DPP +
// permlane16_swap builtin only. Per-position instruction count ~1.5x lower.
__global__ __launch_bounds__(256) void k_routing9(
    const _Float16* __restrict__ votes, const float* __restrict__ bias,
    float* __restrict__ out) {
  __shared__ float so[256 * 9];         // 9 KB, stride 9 + col^g swizzle
  const int tid  = threadIdx.x;
  const int lane = tid & 63;
  const int wv   = tid >> 6;            // 0..3
  const int bid  = blockIdx.x;          // 4096
  const int bv = bid >> 9;
  const int h  = (bid >> 3) & 63;
  const int W0 = (bid & 7) * 8;

  const int half = lane >> 5;           // which of the wave's 2 positions
  const int o    = (lane >> 2) & 7;
  const int g    = lane & 3;            // atom octet: ao = g*8 + j
  const int col  = wv * 2 + half;       // 0..7 within block
  const int w    = W0 + col;

  float bb[8];
  {
    const float4 b0 = *(const float4*)(bias + o * 32 + g * 8);
    const float4 b1 = *(const float4*)(bias + o * 32 + g * 8 + 4);
    bb[0]=b0.x; bb[1]=b0.y; bb[2]=b0.z; bb[3]=b0.w;
    bb[4]=b1.x; bb[5]=b1.y; bb[6]=b1.z; bb[7]=b1.w;
  }

  const _Float16* vb = votes + (size_t)bv * 4194304 + h * 16384 + w * 256
                     + o * 32 + g * 8;
  float v[4][8];
#pragma unroll
  for (int i = 0; i < 4; ++i) {
    half8 hv = *(const half8*)(vb + (size_t)i * 1048576);
#pragma unroll
    for (int j = 0; j < 8; ++j) v[i][j] = (float)hv[j];
  }

  float logit[4], act[8], pr[8];

  // ---- round 0: logits==0 -> route==1/8 exactly; skip the softmax ----
#pragma unroll
  for (int j = 0; j < 8; ++j)
    pr[j] = fmaf(0.125f, (v[0][j] + v[1][j]) + (v[2][j] + v[3][j]), bb[j]);
  {
    float sq = pr[0]*pr[0];
#pragma unroll
    for (int j = 1; j < 8; ++j) sq = fmaf(pr[j], pr[j], sq);
    sq = red_g_add(sq);
    float sc = sq * __builtin_amdgcn_rcpf(1.f + sq)
                  * __builtin_amdgcn_rsqf(sq + EPSF);
#pragma unroll
    for (int j = 0; j < 8; ++j) act[j] = pr[j] * sc;
  }
#pragma unroll
  for (int i = 0; i < 4; ++i) {
    float ag = v[i][0] * act[0];
#pragma unroll
    for (int j = 1; j < 8; ++j) ag = fmaf(v[i][j], act[j], ag);
    logit[i] = red_g_add(ag);
  }

  // ---- rounds 1,2 ----
#pragma unroll
  for (int r = 1; r < 3; ++r) {
    float route[4];
#pragma unroll
    for (int i = 0; i < 4; ++i) {
      float m = red_o2_max(logit[i]);
      float e = __expf(logit[i] - m);
      float s = red_o2_add(e);
      route[i] = e * __builtin_amdgcn_rcpf(s);
    }
#pragma unroll
    for (int j = 0; j < 8; ++j) pr[j] = bb[j];
#pragma unroll
    for (int i = 0; i < 4; ++i)
#pragma unroll
      for (int j = 0; j < 8; ++j)
        pr[j] = fmaf(route[i], v[i][j], pr[j]);
    float sq = pr[0]*pr[0];
#pragma unroll
    for (int j = 1; j < 8; ++j) sq = fmaf(pr[j], pr[j], sq);
    sq = red_g_add(sq);
    float sc = sq * __builtin_amdgcn_rcpf(1.f + sq)
                  * __builtin_amdgcn_rsqf(sq + EPSF);
#pragma unroll
    for (int j = 0; j < 8; ++j) act[j] = pr[j] * sc;
    if (r < 2) {
#pragma unroll
      for (int i = 0; i < 4; ++i) {
        float ag = v[i][0] * act[0];
#pragma unroll
        for (int j = 1; j < 8; ++j) ag = fmaf(v[i][j], act[j], ag);
        logit[i] += red_g_add(ag);
      }
    }
  }

  // stage: row = ao*8 + o = g*64 + j*8 + o  (so g == row>>6); col' = col ^ g.
#pragma unroll
  for (int j = 0; j < 8; ++j)
    so[(g * 64 + j * 8 + o) * 9 + (col ^ g)] = act[j];
  __syncthreads();

  // Writeout: 256 rows x 8 cols. Per pass p: rows p*64..p*64+63 -> g == p,
  // de-swizzle col c -> c ^ p (compile-time per unrolled p).
  float* ob = out + (size_t)bv * 1048576 + h * 64 + W0;
#pragma unroll
  for (int p = 0; p < 4; ++p) {
    int r  = p * 64 + (tid >> 2);
    int c2 = (tid & 3) * 2;
    float lo = so[r * 9 + (c2 ^ p)];
    float hi = so[r * 9 + ((c2 + 1) ^ p)];
    *(float2*)(ob + (size_t)r * 4096 + c2) = make_float2(lo, hi);
  }
}

extern "C" void kernel_launch(void* const* d_in, const int* in_sizes, int n_in,
                              void* d_out, int out_size, void* d_ws, size_t ws_size,
                              hipStream_t stream) {
  const float* x  = (const float*)d_in[0];
  const float* W  = (const float*)d_in[1];
  const float* b  = (const float*)d_in[2];
  float* out = (float*)d_out;

  _Float16* th    = (_Float16*)d_ws;            // 2,097,152 halves (4 MB)
  _Float16* Wp    = th + 2097152;               // 106,496 halves (208 KB)
  _Float16* votes = Wp + 106496;                // 33,554,432 halves (64 MB)

  k_pack2<<<256, 1024, 0, stream>>>(x, th);
  k_packw<<<416, 256, 0, stream>>>(W, Wp);
  k_conv<<<2048, 512, 0, stream>>>(th, Wp, votes);
  k_routing9<<<4096, 256, 0, stream>>>(votes, b, out);
}

// Round 13
// 126.202 us; speedup vs baseline: 1.0523x; 1.0219x over previous
//
#include <hip/hip_runtime.h>
#include <hip/hip_bf16.h>

// Shapes: x(8,16,4,64,64) f32, W(256,16,5,5) f32, b(1,1,8,32) f32
// out(8,32,8,64,64) f32.
//
// Reference reshapes (verified passing through R12):
//   conv input  t2[n,a,h,w] = x[b0, fl&15, ci, fl>>10, (fl>>4)&63],
//     fl = a*4096 + h*64 + w, n = ci*8 + b0
//   votes flat (n,oc,y,x) reinterpreted by routing as (bv,civ,h,w,o,ao):
//     oc = h*4 + (w>>4), y = (w&15)*4 + (o>>1), x = (o&1)*32 + ao
//     -> a routing row consumes ALL conv y's: conv+routing fusion impossible
//        without grid sync; votes must be materialized (audited R13).
// Conv = implicit GEMM on v_mfma_f32_16x16x32_f16 (measured layouts m89/m120).
//
// LEDGER:
//  - Softmax max-subtract removal: FAILED R3+R5. Do not re-try (kept).
//  - Inline-asm permlane swap: FAILED under codegen perturbation (R7/R8).
//    Builtins only (R9/R12-proven).
//  - Routing TLP x2 (R2), ILP x2 (R9): null. 2-pos-per-wave (R12): -2us, kept.
//    Routing ~ max(VALU-issue ~20us, HBM 96MB ~16us): near-bound.
//  - conv: R6 2-stage pipeline best (R11 deeper prefetch + occupancy clamp:
//    worse). Occupancy VGPR-bound at 2 blocks/CU; all isolated levers nulled.
//  - pack2 1024-thread (R10): kept. This round: packw merged into pack2's
//    grid (bit-identical work, one fewer dispatch).

typedef _Float16 half8 __attribute__((ext_vector_type(8)));
typedef _Float16 half4v __attribute__((ext_vector_type(4)));
typedef float floatx4 __attribute__((ext_vector_type(4)));
typedef unsigned uint2v __attribute__((ext_vector_type(2)));

#define EPSF 1e-7f

// ---------- cross-lane reductions (builtins ONLY; no inline asm) ----------
template <int CTRL>
__device__ __forceinline__ float dppmov(float x) {
  return __int_as_float(__builtin_amdgcn_update_dpp(
      0, __float_as_int(x), CTRL, 0xf, 0xf, false));
}
// sum over lane bits 0..1 (atom group g): exact XOR butterfly.
__device__ __forceinline__ float red_g_add(float x) {
  x += dppmov<0xB1>(x);   // quad_perm [1,0,3,2] : ^1
  x += dppmov<0x4E>(x);   // quad_perm [2,3,0,1] : ^2
  return x;
}
// sum over lane bits 2..4 (capsule o, within each 32-lane half):
// ror4+ror8 cover bits 2,3 (rotation-reduce), permlane16_swap covers bit 4.
__device__ __forceinline__ float red_o2_add(float x) {
  x += dppmov<0x124>(x);  // row_ror:4
  x += dppmov<0x128>(x);  // row_ror:8
  uint2v r = __builtin_amdgcn_permlane16_swap(
      __float_as_uint(x), __float_as_uint(x), false, false);
  return __uint_as_float(r[0]) + __uint_as_float(r[1]);
}
__device__ __forceinline__ float red_o2_max(float x) {
  x = fmaxf(x, dppmov<0x124>(x));
  x = fmaxf(x, dppmov<0x128>(x));
  uint2v r = __builtin_amdgcn_permlane16_swap(
      __float_as_uint(x), __float_as_uint(x), false, false);
  return fmaxf(__uint_as_float(r[0]), __uint_as_float(r[1]));
}

// Merged pack: blocks 0..255 = LDS-tile transpose pack (R10/R12 text);
// blocks 256..359 = W repack (104 x 1024 = 106,496 ids exactly).
__global__ __launch_bounds__(1024) void k_pack_all(const float* __restrict__ x,
                                                   const float* __restrict__ W,
                                                   _Float16* __restrict__ th,
                                                   _Float16* __restrict__ Wp) {
  __shared__ float lin[32 * 306 + 18];
  const int bid = blockIdx.x;            // 360 blocks
  const int tid = threadIdx.x;           // 0..1023

  if (bid >= 256) {
    int id = (bid - 256) * 1024 + tid;   // 0..106495 = 26*4096
    int a  = id & 15;
    int oc = (id >> 4) & 255;
    int kk = id >> 12;
    Wp[id] = (kk < 25) ? (_Float16)W[oc * 400 + a * 25 + kk] : (_Float16)0.0f;
    return;
  }

  const int n   = bid >> 3;
  const int a0h = (bid >> 2) & 1;
  const int W0  = (bid & 3) * 16;
  const int ci = n >> 3, b0 = n & 7;
  const float* xb = x + b0 * 262144 + ci * 4096 + W0;

  for (int p = 0; p < 2; ++p) {
    int rr = p * 256 + (tid >> 2);
    int q  = (tid & 3) * 4;
    int a1 = rr >> 5, m = rr & 31;
    float4 v = *(const float4*)(xb + a1 * 16384 + (a0h * 32 + m) * 64 + q);
    float* d = lin + m * 306 + a1 * 18 + q;
    d[0] = v.x; d[1] = v.y; d[2] = v.z; d[3] = v.w;
  }
  __syncthreads();

  _Float16* tb = th + (size_t)n * 65536 + a0h * 32768 + W0 * 128;
  {
    int hh = tid >> 8;
    int w1 = (tid >> 4) & 15;
    int a1 = tid & 15;
    half8 v;
#pragma unroll
    for (int j = 0; j < 8; ++j)
      v[j] = (_Float16)lin[(j * 4 + hh) * 306 + a1 * 18 + w1];
    *(half8*)(tb + hh * 8192 + w1 * 128 + a1 * 8) = v;
  }
}

// Conv: R6's EXACT passing version (2-stage reg pipeline).
__global__ __launch_bounds__(512) void k_conv(const _Float16* __restrict__ th,
                                              const _Float16* __restrict__ Wp,
                                              _Float16* __restrict__ votes) {
  __shared__ _Float16 lds[16384];
  const int orig = blockIdx.x;      // 2048
  const int lid  = (orig & 7) * 256 + (orig >> 3);   // bijective (2048 % 8 == 0)
  const int y = lid & 63;
  const int n = lid >> 6;
  const int tid = threadIdx.x;

  for (int c = tid; c < 680; c += 512) {
    int a0h = c / 340;
    int rem = c - a0h * 340;
    int r   = rem / 68;
    int col = rem - r * 68;
    int row = y + r - 2;
    half8 v = {};
    if (col >= 2 && col <= 65 && row >= 0 && row < 64)
      v = *(const half8*)(th + (size_t)(((n * 2 + a0h) * 64 + row) * 64 + (col - 2)) * 8);
    *(half8*)(lds + c * 8) = v;
  }
  __syncthreads();

  const int lane  = tid & 63;
  const int wv    = tid >> 6;
  const int col16 = lane & 15;
  const int quad  = lane >> 4;
  const int t     = quad >> 1;
  const int a0h   = quad & 1;
  const int m0    = wv * 32;

  floatx4 acc[2][4] = {};

  const _Float16* wbase = Wp + (size_t)t * 4096 + (m0 + col16) * 16 + a0h * 8;
  const _Float16* lbase = lds + (a0h * 340 + col16) * 8;

  half8 bfc[4], awc[2], bfn[4], awn[2];
  {
    const _Float16* lb = lbase + (t ? 1 : 0) * 8;
#pragma unroll
    for (int xt = 0; xt < 4; ++xt)
      bfc[xt] = *(const half8*)(lb + xt * 128);
#pragma unroll
    for (int oct = 0; oct < 2; ++oct)
      awc[oct] = *(const half8*)(wbase + oct * 256);
  }

#pragma unroll
  for (int s = 0; s < 13; ++s) {
    if (s < 12) {
      const int k0 = 2 * (s + 1);
      const int k1 = (2 * (s + 1) + 1 > 24) ? 24 : 2 * (s + 1) + 1;
      const int e0 = (k0 / 5) * 68 + (k0 % 5);
      const int e1 = (k1 / 5) * 68 + (k1 % 5);
      const _Float16* lb = lbase + (t ? e1 : e0) * 8;
#pragma unroll
      for (int xt = 0; xt < 4; ++xt)
        bfn[xt] = *(const half8*)(lb + xt * 128);
#pragma unroll
      for (int oct = 0; oct < 2; ++oct)
        awn[oct] = *(const half8*)(wbase + (size_t)(s + 1) * 8192 + oct * 256);
    }
#pragma unroll
    for (int oct = 0; oct < 2; ++oct)
#pragma unroll
      for (int xt = 0; xt < 4; ++xt)
        acc[oct][xt] = __builtin_amdgcn_mfma_f32_16x16x32_f16(
            awc[oct], bfc[xt], acc[oct][xt], 0, 0, 0);
    if (s < 12) {
#pragma unroll
      for (int xt = 0; xt < 4; ++xt) bfc[xt] = bfn[xt];
#pragma unroll
      for (int oct = 0; oct < 2; ++oct) awc[oct] = awn[oct];
    }
  }

  __syncthreads();
#pragma unroll
  for (int oct = 0; oct < 2; ++oct)
#pragma unroll
    for (int xt = 0; xt < 4; ++xt)
#pragma unroll
      for (int r = 0; r < 4; ++r) {
        int oc = m0 + oct * 16 + quad * 4 + r;
        int xx = xt * 16 + col16;
        int sw = (oc & 15) >> 1;
        lds[oc * 64 + (xx ^ (sw << 3))] = (_Float16)acc[oct][xt][r];
      }
  __syncthreads();
  _Float16* vb2 = votes + (size_t)n * 1048576 + y * 64;
#pragma unroll
  for (int it = 0; it < 4; ++it) {
    int idx = it * 512 + tid;
    int oc  = idx >> 3;
    int x0  = (idx & 7) << 3;
    int sw  = (oc & 15) >> 1;
    half8 hv = *(const half8*)(lds + oc * 64 + (x0 ^ (sw << 3)));
    *(half8*)(vb2 + (size_t)oc * 4096 + x0) = hv;
  }
}

// Routing v9: R12's EXACT passing version (2 positions per wave).
__global__ __launch_bounds__(256) void k_routing9(
    const _Float16* __restrict__ votes, const float* __restrict__ bias,
    float* __restrict__ out) {
  __shared__ float so[256 * 9];         // 9 KB, stride 9 + col^g swizzle
  const int tid  = threadIdx.x;
  const int lane = tid & 63;
  const int wv   = tid >> 6;            // 0..3
  const int bid  = blockIdx.x;          // 4096
  const int bv = bid >> 9;
  const int h  = (bid >> 3) & 63;
  const int W0 = (bid & 7) * 8;

  const int half = lane >> 5;           // which of the wave's 2 positions
  const int o    = (lane >> 2) & 7;
  const int g    = lane & 3;            // atom octet: ao = g*8 + j
  const int col  = wv * 2 + half;       // 0..7 within block
  const int w    = W0 + col;

  float bb[8];
  {
    const float4 b0 = *(const float4*)(bias + o * 32 + g * 8);
    const float4 b1 = *(const float4*)(bias + o * 32 + g * 8 + 4);
    bb[0]=b0.x; bb[1]=b0.y; bb[2]=b0.z; bb[3]=b0.w;
    bb[4]=b1.x; bb[5]=b1.y; bb[6]=b1.z; bb[7]=b1.w;
  }

  const _Float16* vb = votes + (size_t)bv * 4194304 + h * 16384 + w * 256
                     + o * 32 + g * 8;
  float v[4][8];
#pragma unroll
  for (int i = 0; i < 4; ++i) {
    half8 hv = *(const half8*)(vb + (size_t)i * 1048576);
#pragma unroll
    for (int j = 0; j < 8; ++j) v[i][j] = (float)hv[j];
  }

  float logit[4], act[8], pr[8];

  // ---- round 0: logits==0 -> route==1/8 exactly; skip the softmax ----
#pragma unroll
  for (int j = 0; j < 8; ++j)
    pr[j] = fmaf(0.125f, (v[0][j] + v[1][j]) + (v[2][j] + v[3][j]), bb[j]);
  {
    float sq = pr[0]*pr[0];
#pragma unroll
    for (int j = 1; j < 8; ++j) sq = fmaf(pr[j], pr[j], sq);
    sq = red_g_add(sq);
    float sc = sq * __builtin_amdgcn_rcpf(1.f + sq)
                  * __builtin_amdgcn_rsqf(sq + EPSF);
#pragma unroll
    for (int j = 0; j < 8; ++j) act[j] = pr[j] * sc;
  }
#pragma unroll
  for (int i = 0; i < 4; ++i) {
    float ag = v[i][0] * act[0];
#pragma unroll
    for (int j = 1; j < 8; ++j) ag = fmaf(v[i][j], act[j], ag);
    logit[i] = red_g_add(ag);
  }

  // ---- rounds 1,2 ----
#pragma unroll
  for (int r = 1; r < 3; ++r) {
    float route[4];
#pragma unroll
    for (int i = 0; i < 4; ++i) {
      float m = red_o2_max(logit[i]);
      float e = __expf(logit[i] - m);
      float s = red_o2_add(e);
      route[i] = e * __builtin_amdgcn_rcpf(s);
    }
#pragma unroll
    for (int j = 0; j < 8; ++j) pr[j] = bb[j];
#pragma unroll
    for (int i = 0; i < 4; ++i)
#pragma unroll
      for (int j = 0; j < 8; ++j)
        pr[j] = fmaf(route[i], v[i][j], pr[j]);
    float sq = pr[0]*pr[0];
#pragma unroll
    for (int j = 1; j < 8; ++j) sq = fmaf(pr[j], pr[j], sq);
    sq = red_g_add(sq);
    float sc = sq * __builtin_amdgcn_rcpf(1.f + sq)
                  * __builtin_amdgcn_rsqf(sq + EPSF);
#pragma unroll
    for (int j = 0; j < 8; ++j) act[j] = pr[j] * sc;
    if (r < 2) {
#pragma unroll
      for (int i = 0; i < 4; ++i) {
        float ag = v[i][0] * act[0];
#pragma unroll
        for (int j = 1; j < 8; ++j) ag = fmaf(v[i][j], act[j], ag);
        logit[i] += red_g_add(ag);
      }
    }
  }

  // stage: row = ao*8 + o = g*64 + j*8 + o  (so g == row>>6); col' = col ^ g.
#pragma unroll
  for (int j = 0; j < 8; ++j)
    so[(g * 64 + j * 8 + o) * 9 + (col ^ g)] = act[j];
  __syncthreads();

  // Writeout: 256 rows x 8 cols. Per pass p: rows p*64..p*64+63 -> g == p,
  // de-swizzle col c -> c ^ p (compile-time per unrolled p).
  float* ob = out + (size_t)bv * 1048576 + h * 64 + W0;
#pragma unroll
  for (int p = 0; p < 4; ++p) {
    int r  = p * 64 + (tid >> 2);
    int c2 = (tid & 3) * 2;
    float lo = so[r * 9 + (c2 ^ p)];
    float hi = so[r * 9 + ((c2 + 1) ^ p)];
    *(float2*)(ob + (size_t)r * 4096 + c2) = make_float2(lo, hi);
  }
}

extern "C" void kernel_launch(void* const* d_in, const int* in_sizes, int n_in,
                              void* d_out, int out_size, void* d_ws, size_t ws_size,
                              hipStream_t stream) {
  const float* x  = (const float*)d_in[0];
  const float* W  = (const float*)d_in[1];
  const float* b  = (const float*)d_in[2];
  float* out = (float*)d_out;

  _Float16* th    = (_Float16*)d_ws;            // 2,097,152 halves (4 MB)
  _Float16* Wp    = th + 2097152;               // 106,496 halves (208 KB)
  _Float16* votes = Wp + 106496;                // 33,554,432 halves (64 MB)

  k_pack_all<<<360, 1024, 0, stream>>>(x, W, th, Wp);
  k_conv<<<2048, 512, 0, stream>>>(th, Wp, votes);
  k_routing9<<<4096, 256, 0, stream>>>(votes, b, out);
}